// Round 1
// baseline (6391.691 us; speedup 1.0000x reference)
//
#include <hip/hip_runtime.h>
#include <hip/hip_bf16.h>

#define SEQ  1024
#define BATCH 128
#define EMB   512
#define HID   512
#define KDIM 1024   // EMB+HID
#define NZ   2048   // 4*HID

typedef __bf16 bf16;
typedef __attribute__((ext_vector_type(8))) __bf16 bf16x8;
typedef __attribute__((ext_vector_type(4))) __bf16 bf16x4;
typedef __attribute__((ext_vector_type(4))) float f32x4;
typedef __attribute__((ext_vector_type(4))) unsigned int uint4v;

// W [1024][2048] fp32 row-major  ->  Ws bf16 k-blocked: Ws[(kb*2048 + n)*32 + ko],
// kb = k/32, ko = k%32. B-fragment load for (kb, n0): lane L (ln=L&15, q=L>>4)
// reads 8 contiguous bf16 at (kb*2048 + n0 + ln)*32 + q*8 -> wave covers one
// contiguous 1 KiB segment (perfectly coalesced).
__global__ void convert_w(const float* __restrict__ W, bf16* __restrict__ Ws) {
    int idx = blockIdx.x * 256 + threadIdx.x;   // 0 .. 1024*2048-1, coalesced in n
    int k = idx >> 11;
    int n = idx & 2047;
    float w = W[idx];
    int kb = k >> 5, ko = k & 31;
    Ws[((kb * NZ + n) << 5) + ko] = (bf16)w;
}

// One LSTM timestep. Grid: 256 wgs (8 batch-groups x 32 col-groups), 256 thr.
// wg tile: 16 batches x 16 h-cols, all 4 gates (wave w = gate w).
__global__ __launch_bounds__(256) void lstm_step(
    const float* __restrict__ x,      // [SEQ][BATCH][EMB] fp32
    const bf16*  __restrict__ Ws,     // k-blocked bf16 weights
    const float* __restrict__ bias,   // [2048] fp32
    const bf16*  __restrict__ h_in,   // [BATCH][HID] bf16 (t-1)
    bf16*        __restrict__ h_out,  // [BATCH][HID] bf16 (t)
    float*       __restrict__ c,      // [BATCH][HID] fp32 persistent state
    float*       __restrict__ out,    // [SEQ][BATCH][HID] fp32 (+ hT, cT tail)
    int t)
{
    // A-tile: 16 rows x 1024 k, bf16, row stride padded 1024->1032
    __shared__ bf16 Ash[16 * 1032];          // 33,024 B
    __shared__ float zsh[4][16][17];         // 4,352 B

    const int tid  = threadIdx.x;
    const int wave = tid >> 6;
    const int lane = tid & 63;
    const int ln   = lane & 15;
    const int q    = lane >> 4;

    const int gb = blockIdx.x >> 5;          // batch group 0..7
    const int gc = blockIdx.x & 31;          // h-col group 0..31
    const int m0 = gb * 16;                  // batch base
    const int c0 = gc * 16;                  // h-col base
    const int n0 = wave * 512 + c0;          // z-col base for this wave (gate = wave)

    // ---- Stage x part of A: rows m0..m0+15, k 0..511 (fp32 -> bf16) ----
    #pragma unroll
    for (int i = 0; i < 8; ++i) {
        int f4  = (tid + i * 256) * 4;       // flat float index 0..8191
        int row = f4 >> 9;
        int kk  = f4 & 511;
        float4 v = *(const float4*)(x + ((size_t)t * BATCH + m0 + row) * EMB + kk);
        bf16x4 pv = { (bf16)v.x, (bf16)v.y, (bf16)v.z, (bf16)v.w };
        *(bf16x4*)&Ash[row * 1032 + kk] = pv;
    }
    // ---- Stage h part of A: rows m0..m0+15, k 512..1023 (bf16 passthrough) ----
    if (t == 0) {
        #pragma unroll
        for (int i = 0; i < 4; ++i) {
            int e8  = (tid + i * 256) * 8;   // flat bf16 index 0..8191
            int row = e8 >> 9;
            int kk  = e8 & 511;
            uint4v z = {0u, 0u, 0u, 0u};
            *(uint4v*)&Ash[row * 1032 + 512 + kk] = z;
        }
    } else {
        #pragma unroll
        for (int i = 0; i < 4; ++i) {
            int e8  = (tid + i * 256) * 8;
            int row = e8 >> 9;
            int kk  = e8 & 511;
            *(uint4v*)&Ash[row * 1032 + 512 + kk] =
                *(const uint4v*)(h_in + (size_t)(m0 + row) * HID + kk);
        }
    }
    __syncthreads();

    // ---- GEMM: 16x16 z-tile for this wave's gate, K=1024 ----
    f32x4 acc = {0.f, 0.f, 0.f, 0.f};
    #pragma unroll 8
    for (int kb = 0; kb < 32; ++kb) {
        // A-frag: lane holds A[m=ln][k=kb*32 + q*8 + j]
        bf16x8 a = *(const bf16x8*)&Ash[ln * 1032 + kb * 32 + q * 8];
        // B-frag: lane holds B[k=kb*32 + q*8 + j][n=n0+ln]
        bf16x8 b = *(const bf16x8*)&Ws[((kb * NZ + n0 + ln) << 5) + q * 8];
        acc = __builtin_amdgcn_mfma_f32_16x16x32_bf16(a, b, acc, 0, 0, 0);
    }

    // C/D layout: col = ln, row = q*4 + r  (m89-verified)
    float bn = bias[n0 + ln];
    #pragma unroll
    for (int r = 0; r < 4; ++r)
        zsh[wave][q * 4 + r][ln] = acc[r] + bn;
    __syncthreads();

    // ---- Gates + state update: thread t -> (batch-local, hcol-local) ----
    int bl = tid >> 4;
    int hl = tid & 15;
    float zi = zsh[0][bl][hl];
    float zf = zsh[1][bl][hl];
    float zg = zsh[2][bl][hl];
    float zo = zsh[3][bl][hl];

    int gbatch = m0 + bl;
    int ghid   = c0 + hl;
    size_t cidx = (size_t)gbatch * HID + ghid;

    float c_old = (t == 0) ? 0.f : c[cidx];
    float si = 1.f / (1.f + __expf(-zi));
    float sf = 1.f / (1.f + __expf(-zf));
    float so = 1.f / (1.f + __expf(-zo));
    float tg = tanhf(zg);
    float cn = sf * c_old + si * tg;
    float hn = so * tanhf(cn);

    c[cidx]     = cn;
    h_out[cidx] = (bf16)hn;
    out[((size_t)t * BATCH + gbatch) * HID + ghid] = hn;
    if (t == SEQ - 1) {
        out[(size_t)SEQ * BATCH * HID + cidx] = hn;                 // hT
        out[(size_t)SEQ * BATCH * HID + (size_t)BATCH * HID + cidx] = cn;  // cT
    }
}

extern "C" void kernel_launch(void* const* d_in, const int* in_sizes, int n_in,
                              void* d_out, int out_size, void* d_ws, size_t ws_size,
                              hipStream_t stream) {
    const float* x    = (const float*)d_in[0];
    const float* W    = (const float*)d_in[1];
    const float* bias = (const float*)d_in[2];
    float* out = (float*)d_out;

    char* ws = (char*)d_ws;
    bf16*  Ws = (bf16*)ws;                                   // 4 MB
    bf16*  h0 = (bf16*)(ws + 4 * 1024 * 1024);               // 128 KB
    bf16*  h1 = (bf16*)(ws + 4 * 1024 * 1024 + 128 * 1024);  // 128 KB
    float* c  = (float*)(ws + 4 * 1024 * 1024 + 256 * 1024); // 256 KB

    convert_w<<<dim3(8192), dim3(256), 0, stream>>>(W, Ws);

    for (int t = 0; t < SEQ; ++t) {
        bf16* hin  = (t & 1) ? h1 : h0;
        bf16* hout = (t & 1) ? h0 : h1;
        lstm_step<<<dim3(256), dim3(256), 0, stream>>>(x, Ws, bias, hin, hout, c, out, t);
    }
}